// Round 4
// baseline (1253.900 us; speedup 1.0000x reference)
//
#include <hip/hip_runtime.h>

#define TT 512
#define BIGS 1.4426950408889634e10f   // BIG(1e10) * log2(e), scaled domain
#define LOG2E 1.4426950408889634f
#define M2L  (-2.0f * 1.4426950408889634f)
#define LN2F 0.69314718055994531f

typedef _Float16 h2 __attribute__((ext_vector_type(2)));

__device__ __forceinline__ unsigned pk(float a, float b) {
    h2 v; v.x = (_Float16)a; v.y = (_Float16)b;
    return __builtin_bit_cast(unsigned, v);
}

#if __has_builtin(__builtin_amdgcn_fdot2)
#define FDOT2(a, b, c) __builtin_amdgcn_fdot2(__builtin_bit_cast(h2, (a)), \
                                              __builtin_bit_cast(h2, (b)), (c), false)
#else
__device__ __forceinline__ float fdot2_sw(unsigned a, unsigned b, float c) {
    h2 ha = __builtin_bit_cast(h2, a), hb = __builtin_bit_cast(h2, b);
    return c + (float)ha.x * (float)hb.x + (float)ha.y * (float)hb.y;
}
#define FDOT2(a, b, c) fdot2_sw((a), (b), (c))
#endif

// ---------------------------------------------------------------------------
// Fused SoftDTW. 512-thread blocks = 8 waves = 8 samples (2 waves/SIMD for
// latency hiding). Each wave: lane t owns X rows 8t..8t+7 in registers;
// Z rows ride a register queue (one slot shuffled up per diagonal, lane 0
// refills from LDS). Software-pipelined step: queue shift for diag kd+1 at
// the TOP, softmin for diag kd in the middle (consumes dd from previous
// step), dot-products for diag kd+1 at the BOTTOM -> every ds_permute has
// ~250 cyc of math between issue and use. Base-2 scaled domain.
// ---------------------------------------------------------------------------
__global__ __launch_bounds__(512) void k_fused(const float* __restrict__ X,
                                               const float* __restrict__ Z,
                                               const float* __restrict__ w,
                                               float* __restrict__ out) {
    const int tt = threadIdx.x;
    const int t  = tt & 63;          // lane within wave
    const int wv = tt >> 6;          // wave = sample slot
    const int n  = blockIdx.x * 8 + wv;

    __shared__ uint4 ZhU[1024];      // Z rows as 8 x h2 (2 uint4 per row)
    __shared__ float Zs2f[512];      // LOG2E * |z_row|^2

    // ---- stage Z into LDS: thread tt handles row tt ----
    {
        const int r = tt;
        const float4* zp = (const float4*)(Z + (size_t)r * 16);
        const float4 a0 = zp[0], a1 = zp[1], a2 = zp[2], a3 = zp[3];
        float sv = 0.0f;
        sv = fmaf(a0.x, a0.x, sv); sv = fmaf(a0.y, a0.y, sv);
        sv = fmaf(a0.z, a0.z, sv); sv = fmaf(a0.w, a0.w, sv);
        sv = fmaf(a1.x, a1.x, sv); sv = fmaf(a1.y, a1.y, sv);
        sv = fmaf(a1.z, a1.z, sv); sv = fmaf(a1.w, a1.w, sv);
        sv = fmaf(a2.x, a2.x, sv); sv = fmaf(a2.y, a2.y, sv);
        sv = fmaf(a2.z, a2.z, sv); sv = fmaf(a2.w, a2.w, sv);
        sv = fmaf(a3.x, a3.x, sv); sv = fmaf(a3.y, a3.y, sv);
        sv = fmaf(a3.z, a3.z, sv); sv = fmaf(a3.w, a3.w, sv);
        ZhU[2 * r]     = make_uint4(pk(a0.x, a0.y), pk(a0.z, a0.w),
                                    pk(a1.x, a1.y), pk(a1.z, a1.w));
        ZhU[2 * r + 1] = make_uint4(pk(a2.x, a2.y), pk(a2.z, a2.w),
                                    pk(a3.x, a3.y), pk(a3.z, a3.w));
        Zs2f[r] = LOG2E * sv;
    }

    // ---- X rows for this lane -> registers ----
    unsigned Xu[8][8];
    float    xs2[8];
    const float* xp = X + ((size_t)n * TT + 8 * t) * 16;
#pragma unroll
    for (int q = 0; q < 8; ++q) {
        const float4* xr = (const float4*)(xp + q * 16);
        const float4 a0 = xr[0], a1 = xr[1], a2 = xr[2], a3 = xr[3];
        float sv = 0.0f;
        sv = fmaf(a0.x, a0.x, sv); sv = fmaf(a0.y, a0.y, sv);
        sv = fmaf(a0.z, a0.z, sv); sv = fmaf(a0.w, a0.w, sv);
        sv = fmaf(a1.x, a1.x, sv); sv = fmaf(a1.y, a1.y, sv);
        sv = fmaf(a1.z, a1.z, sv); sv = fmaf(a1.w, a1.w, sv);
        sv = fmaf(a2.x, a2.x, sv); sv = fmaf(a2.y, a2.y, sv);
        sv = fmaf(a2.z, a2.z, sv); sv = fmaf(a2.w, a2.w, sv);
        sv = fmaf(a3.x, a3.x, sv); sv = fmaf(a3.y, a3.y, sv);
        sv = fmaf(a3.z, a3.z, sv); sv = fmaf(a3.w, a3.w, sv);
        xs2[q] = LOG2E * sv;
        Xu[q][0] = pk(a0.x, a0.y); Xu[q][1] = pk(a0.z, a0.w);
        Xu[q][2] = pk(a1.x, a1.y); Xu[q][3] = pk(a1.z, a1.w);
        Xu[q][4] = pk(a2.x, a2.y); Xu[q][5] = pk(a2.z, a2.w);
        Xu[q][6] = pk(a3.x, a3.y); Xu[q][7] = pk(a3.z, a3.w);
    }
    __syncthreads();

    // ---- Z queue init: all slots = row 0 (exact for lane0/q0 at kd=0) ----
    unsigned Zu[8][8];
    float    Zq2[8];
    {
        const uint4 q0 = ZhU[0], q1 = ZhU[1];
        const float qz = Zs2f[0];
        const unsigned fu[8] = {q0.x, q0.y, q0.z, q0.w, q1.x, q1.y, q1.z, q1.w};
#pragma unroll
        for (int s = 0; s < 8; ++s) {
#pragma unroll
            for (int r = 0; r < 8; ++r) Zu[s][r] = fu[r];
            Zq2[s] = qz;
        }
    }

    float A[8], B[8], D0[8], D1[8];
#pragma unroll
    for (int q = 0; q < 8; ++q) { A[q] = BIGS; B[q] = BIGS; }

    // dd for diag 0 (slot mapping = identity); only lane0/q0 is a real cell
#pragma unroll
    for (int q = 0; q < 8; ++q) {
        float acc = 0.0f;
#pragma unroll
        for (int r = 0; r < 8; ++r) acc = FDOT2(Zu[q][r], Xu[q][r], acc);
        D0[q] = fmaf(M2L, acc, xs2[q] + Zq2[q]);
    }

    // One diagonal kd = kd8 + pp. P = diag kd-1, Q = diag kd-2 (becomes kd).
    // DC = D' for diag kd (from previous step); DN receives D' for kd+1.
    // Queue mapping at diag kd: cell q <-> slot (q - kd) & 7.
#define STEP(pp, P, Q, DC, DN)                                                 \
    {                                                                          \
        const int kd = kd8 + (pp);                                             \
        /* 1. shift queue to diag kd+1 alignment; lane 0 refills row fr */     \
        const int fr = (kd + 1 > 511) ? 511 : (kd + 1);                        \
        const uint4 f0 = ZhU[2 * fr], f1 = ZhU[2 * fr + 1];                    \
        const float fz2 = Zs2f[fr];                                            \
        {                                                                      \
            const int sn = (7 - (pp)) & 7;                                     \
            const unsigned fu[8] = {f0.x, f0.y, f0.z, f0.w,                    \
                                    f1.x, f1.y, f1.z, f1.w};                   \
            _Pragma("unroll")                                                  \
            for (int r = 0; r < 8; ++r) {                                      \
                const unsigned sh = __shfl_up(Zu[sn][r], 1);                   \
                Zu[sn][r] = (t == 0) ? fu[r] : sh;                             \
            }                                                                  \
            const float shz = __shfl_up(Zq2[sn], 1);                           \
            Zq2[sn] = (t == 0) ? fz2 : shz;                                    \
        }                                                                      \
        /* 2. boundary values from lane t-1 (consumed LAST in softmin) */      \
        float s1 = __shfl_up(P[7], 1);                                         \
        float s2 = __shfl_up(Q[7], 1);                                         \
        if (t == 0) { s1 = BIGS; s2 = BIGS; }                                  \
        /* 3. softmin for diag kd using DC (descending q: s1/s2 last) */       \
        _Pragma("unroll")                                                      \
        for (int q = 7; q >= 0; --q) {                                         \
            const float u1 = q ? P[q - 1] : s1;                                \
            const float u2 = q ? Q[q - 1] : s2;                                \
            const float pl = P[q];                                             \
            const float mn = fminf(fminf(u1, pl), u2);                         \
            const float md = __builtin_amdgcn_fmed3f(u1, pl, u2);              \
            const float mx = fmaxf(fmaxf(u1, pl), u2);                         \
            const float sm = 1.0f + exp2f(mn - md) + exp2f(mn - mx);           \
            Q[q] = DC[q] + mn - log2f(sm);                                     \
        }                                                                      \
        /* 4. j==0 edge repair (exact: softmin(u,BIG,BIG) == u) */             \
        if (kd < 512 && t == (kd >> 3)) {                                      \
            Q[(pp)] = DC[(pp)] + ((pp) == 0 ? (kd ? s1 : 0.0f) : P[(pp)-1]);   \
        }                                                                      \
        /* 5. dd for diag kd+1: slot s = (q - kd - 1) & 7 */                   \
        _Pragma("unroll")                                                      \
        for (int q = 0; q < 8; ++q) {                                          \
            const int s = (q - (pp) - 1) & 7;                                  \
            float acc = 0.0f;                                                  \
            _Pragma("unroll")                                                  \
            for (int r = 0; r < 8; ++r) acc = FDOT2(Zu[s][r], Xu[q][r], acc);  \
            DN[q] = fmaf(M2L, acc, xs2[q] + Zq2[s]);                           \
        }                                                                      \
    }

#pragma unroll 1
    for (int kd8 = 0; kd8 < 1024; kd8 += 8) {
        STEP(0, A, B, D0, D1) STEP(1, B, A, D1, D0)
        STEP(2, A, B, D0, D1) STEP(3, B, A, D1, D0)
        STEP(4, A, B, D0, D1) STEP(5, B, A, D1, D0)
        STEP(6, A, B, D0, D1) STEP(7, B, A, D1, D0)
    }
#undef STEP

    // diag 1022 result is in B (pp=6); lane 63 B[7] = R[T,T] scaled
    if (t == 63) atomicAdd(out, w[n] * B[7] * LN2F);
}

__global__ void k_zero(float* out) {
    if (threadIdx.x == 0) out[0] = 0.0f;
}

extern "C" void kernel_launch(void* const* d_in, const int* in_sizes, int n_in,
                              void* d_out, int out_size, void* d_ws, size_t ws_size,
                              hipStream_t stream) {
    const float* X = (const float*)d_in[0];   // (64, 512, 16) f32
    const float* w = (const float*)d_in[1];   // (64,) f32
    const float* Z = (const float*)d_in[2];   // (512, 16) f32
    float* out = (float*)d_out;               // scalar f32

    hipLaunchKernelGGL(k_zero, dim3(1), dim3(64), 0, stream, out);
    hipLaunchKernelGGL(k_fused, dim3(8), dim3(512), 0, stream, X, Z, w, out);
}

// Round 5
// 757.389 us; speedup vs baseline: 1.6556x; 1.6556x over previous
//
#include <hip/hip_runtime.h>

#define TT 512
#define BIGS 1.4426950408889634e10f   // BIG(1e10) * log2(e), scaled domain
#define LOG2E 1.4426950408889634f
#define M2L  (-2.0f * 1.4426950408889634f)
#define LN2F 0.69314718055994531f

typedef _Float16 h2 __attribute__((ext_vector_type(2)));

__device__ __forceinline__ unsigned pk(float a, float b) {
    h2 v; v.x = (_Float16)a; v.y = (_Float16)b;
    return __builtin_bit_cast(unsigned, v);
}

#if __has_builtin(__builtin_amdgcn_fdot2)
#define FDOT2(a, b, c) __builtin_amdgcn_fdot2(__builtin_bit_cast(h2, (a)), \
                                              __builtin_bit_cast(h2, (b)), (c), false)
#else
__device__ __forceinline__ float fdot2_sw(unsigned a, unsigned b, float c) {
    h2 ha = __builtin_bit_cast(h2, a), hb = __builtin_bit_cast(h2, b);
    return c + (float)ha.x * (float)hb.x + (float)ha.y * (float)hb.y;
}
#define FDOT2(a, b, c) fdot2_sw((a), (b), (c))
#endif

// ---------------------------------------------------------------------------
// Fused SoftDTW. 256-thread blocks = 4 waves = 4 samples, ONE wave per SIMD
// (launch_bounds(256,1) -> VGPR cap 512: the ~200 live registers stay in
// registers; round-4's (512) default capped at 120 and spilled the arrays).
// Per wave: lane t owns X rows 8t..8t+7 in registers; Z rows ride a register
// queue (one slot shuffled up per diagonal, lane 0 refills from LDS).
// Software-pipelined step: queue shift + boundary shuffles at the TOP,
// softmin (consuming previous step's dd) in the middle, next diagonal's
// dot-products at the BOTTOM. Base-2 scaled domain (values = true*log2e).
// ---------------------------------------------------------------------------
__global__ __launch_bounds__(256, 1) void k_fused(const float* __restrict__ X,
                                                  const float* __restrict__ Z,
                                                  const float* __restrict__ w,
                                                  float* __restrict__ out) {
    const int tt = threadIdx.x;
    const int t  = tt & 63;          // lane within wave
    const int wv = tt >> 6;          // wave = sample slot (0..3)
    const int n  = blockIdx.x * 4 + wv;

    __shared__ uint4 ZhU[1024];      // Z rows as 8 x h2 (2 uint4 per row)
    __shared__ float Zs2f[512];      // LOG2E * |z_row|^2

    // ---- stage Z into LDS: thread tt handles rows tt and tt+256 ----
#pragma unroll
    for (int h = 0; h < 2; ++h) {
        const int r = tt + h * 256;
        const float4* zp = (const float4*)(Z + (size_t)r * 16);
        const float4 a0 = zp[0], a1 = zp[1], a2 = zp[2], a3 = zp[3];
        float sv = 0.0f;
        sv = fmaf(a0.x, a0.x, sv); sv = fmaf(a0.y, a0.y, sv);
        sv = fmaf(a0.z, a0.z, sv); sv = fmaf(a0.w, a0.w, sv);
        sv = fmaf(a1.x, a1.x, sv); sv = fmaf(a1.y, a1.y, sv);
        sv = fmaf(a1.z, a1.z, sv); sv = fmaf(a1.w, a1.w, sv);
        sv = fmaf(a2.x, a2.x, sv); sv = fmaf(a2.y, a2.y, sv);
        sv = fmaf(a2.z, a2.z, sv); sv = fmaf(a2.w, a2.w, sv);
        sv = fmaf(a3.x, a3.x, sv); sv = fmaf(a3.y, a3.y, sv);
        sv = fmaf(a3.z, a3.z, sv); sv = fmaf(a3.w, a3.w, sv);
        ZhU[2 * r]     = make_uint4(pk(a0.x, a0.y), pk(a0.z, a0.w),
                                    pk(a1.x, a1.y), pk(a1.z, a1.w));
        ZhU[2 * r + 1] = make_uint4(pk(a2.x, a2.y), pk(a2.z, a2.w),
                                    pk(a3.x, a3.y), pk(a3.z, a3.w));
        Zs2f[r] = LOG2E * sv;
    }

    // ---- X rows for this lane -> registers ----
    unsigned Xu[8][8];
    float    xs2[8];
    const float* xp = X + ((size_t)n * TT + 8 * t) * 16;
#pragma unroll
    for (int q = 0; q < 8; ++q) {
        const float4* xr = (const float4*)(xp + q * 16);
        const float4 a0 = xr[0], a1 = xr[1], a2 = xr[2], a3 = xr[3];
        float sv = 0.0f;
        sv = fmaf(a0.x, a0.x, sv); sv = fmaf(a0.y, a0.y, sv);
        sv = fmaf(a0.z, a0.z, sv); sv = fmaf(a0.w, a0.w, sv);
        sv = fmaf(a1.x, a1.x, sv); sv = fmaf(a1.y, a1.y, sv);
        sv = fmaf(a1.z, a1.z, sv); sv = fmaf(a1.w, a1.w, sv);
        sv = fmaf(a2.x, a2.x, sv); sv = fmaf(a2.y, a2.y, sv);
        sv = fmaf(a2.z, a2.z, sv); sv = fmaf(a2.w, a2.w, sv);
        sv = fmaf(a3.x, a3.x, sv); sv = fmaf(a3.y, a3.y, sv);
        sv = fmaf(a3.z, a3.z, sv); sv = fmaf(a3.w, a3.w, sv);
        xs2[q] = LOG2E * sv;
        Xu[q][0] = pk(a0.x, a0.y); Xu[q][1] = pk(a0.z, a0.w);
        Xu[q][2] = pk(a1.x, a1.y); Xu[q][3] = pk(a1.z, a1.w);
        Xu[q][4] = pk(a2.x, a2.y); Xu[q][5] = pk(a2.z, a2.w);
        Xu[q][6] = pk(a3.x, a3.y); Xu[q][7] = pk(a3.z, a3.w);
    }
    __syncthreads();

    // ---- Z queue init: all slots = row 0 (exact for lane0/q0 at kd=0) ----
    unsigned Zu[8][8];
    float    Zq2[8];
    {
        const uint4 q0 = ZhU[0], q1 = ZhU[1];
        const float qz = Zs2f[0];
        const unsigned fu[8] = {q0.x, q0.y, q0.z, q0.w, q1.x, q1.y, q1.z, q1.w};
#pragma unroll
        for (int s = 0; s < 8; ++s) {
#pragma unroll
            for (int r = 0; r < 8; ++r) Zu[s][r] = fu[r];
            Zq2[s] = qz;
        }
    }

    float A[8], B[8], D0[8], D1[8];
#pragma unroll
    for (int q = 0; q < 8; ++q) { A[q] = BIGS; B[q] = BIGS; }

    // dd for diag 0 (slot mapping = identity); only lane0/q0 is a real cell
#pragma unroll
    for (int q = 0; q < 8; ++q) {
        float acc = 0.0f;
#pragma unroll
        for (int r = 0; r < 8; ++r) acc = FDOT2(Zu[q][r], Xu[q][r], acc);
        D0[q] = fmaf(M2L, acc, xs2[q] + Zq2[q]);
    }

    // One diagonal kd = kd8 + pp. P = diag kd-1, Q = diag kd-2 (becomes kd).
    // DC = D' for diag kd (from previous step); DN receives D' for kd+1.
    // Queue mapping at diag kd: cell q <-> slot (q - kd) & 7.
#define STEP(pp, P, Q, DC, DN)                                                 \
    {                                                                          \
        const int kd = kd8 + (pp);                                             \
        /* 1. shift queue to diag kd+1 alignment; lane 0 refills row fr */     \
        const int fr = (kd + 1 > 511) ? 511 : (kd + 1);                        \
        const uint4 f0 = ZhU[2 * fr], f1 = ZhU[2 * fr + 1];                    \
        const float fz2 = Zs2f[fr];                                            \
        {                                                                      \
            const int sn = (7 - (pp)) & 7;                                     \
            const unsigned fu[8] = {f0.x, f0.y, f0.z, f0.w,                    \
                                    f1.x, f1.y, f1.z, f1.w};                   \
            _Pragma("unroll")                                                  \
            for (int r = 0; r < 8; ++r) {                                      \
                const unsigned sh = __shfl_up(Zu[sn][r], 1);                   \
                Zu[sn][r] = (t == 0) ? fu[r] : sh;                             \
            }                                                                  \
            const float shz = __shfl_up(Zq2[sn], 1);                           \
            Zq2[sn] = (t == 0) ? fz2 : shz;                                    \
        }                                                                      \
        /* 2. boundary values from lane t-1 (consumed LAST in softmin) */      \
        float s1 = __shfl_up(P[7], 1);                                         \
        float s2 = __shfl_up(Q[7], 1);                                         \
        if (t == 0) { s1 = BIGS; s2 = BIGS; }                                  \
        /* 3. softmin for diag kd using DC (descending q: s1/s2 last) */       \
        _Pragma("unroll")                                                      \
        for (int q = 7; q >= 0; --q) {                                         \
            const float u1 = q ? P[q - 1] : s1;                                \
            const float u2 = q ? Q[q - 1] : s2;                                \
            const float pl = P[q];                                             \
            const float mn = fminf(fminf(u1, pl), u2);                         \
            const float md = __builtin_amdgcn_fmed3f(u1, pl, u2);              \
            const float mx = fmaxf(fmaxf(u1, pl), u2);                         \
            const float sm = 1.0f + exp2f(mn - md) + exp2f(mn - mx);           \
            Q[q] = DC[q] + mn - log2f(sm);                                     \
        }                                                                      \
        /* 4. j==0 edge repair (exact: softmin(u,BIG,BIG) == u) */             \
        if (kd < 512 && t == (kd >> 3)) {                                      \
            Q[(pp)] = DC[(pp)] + ((pp) == 0 ? (kd ? s1 : 0.0f) : P[(pp)-1]);   \
        }                                                                      \
        /* 5. dd for diag kd+1: slot s = (q - kd - 1) & 7 */                   \
        _Pragma("unroll")                                                      \
        for (int q = 0; q < 8; ++q) {                                          \
            const int s = (q - (pp) - 1) & 7;                                  \
            float acc = 0.0f;                                                  \
            _Pragma("unroll")                                                  \
            for (int r = 0; r < 8; ++r) acc = FDOT2(Zu[s][r], Xu[q][r], acc);  \
            DN[q] = fmaf(M2L, acc, xs2[q] + Zq2[s]);                           \
        }                                                                      \
    }

#pragma unroll 1
    for (int kd8 = 0; kd8 < 1024; kd8 += 8) {
        STEP(0, A, B, D0, D1) STEP(1, B, A, D1, D0)
        STEP(2, A, B, D0, D1) STEP(3, B, A, D1, D0)
        STEP(4, A, B, D0, D1) STEP(5, B, A, D1, D0)
        STEP(6, A, B, D0, D1) STEP(7, B, A, D1, D0)
    }
#undef STEP

    // diag 1022 result is in B (pp=6); lane 63 B[7] = R[T,T] scaled
    if (t == 63) atomicAdd(out, w[n] * B[7] * LN2F);
}

__global__ void k_zero(float* out) {
    if (threadIdx.x == 0) out[0] = 0.0f;
}

extern "C" void kernel_launch(void* const* d_in, const int* in_sizes, int n_in,
                              void* d_out, int out_size, void* d_ws, size_t ws_size,
                              hipStream_t stream) {
    const float* X = (const float*)d_in[0];   // (64, 512, 16) f32
    const float* w = (const float*)d_in[1];   // (64,) f32
    const float* Z = (const float*)d_in[2];   // (512, 16) f32
    float* out = (float*)d_out;               // scalar f32

    hipLaunchKernelGGL(k_zero, dim3(1), dim3(64), 0, stream, out);
    hipLaunchKernelGGL(k_fused, dim3(16), dim3(256), 0, stream, X, Z, w, out);
}

// Round 6
// 466.857 us; speedup vs baseline: 2.6858x; 1.6223x over previous
//
#include <hip/hip_runtime.h>

#define TT 512
#define BIGS 1.4426950408889634e10f   // BIG(1e10) * log2(e), scaled domain
#define LOG2E 1.4426950408889634f
#define M2L  (-2.0f * 1.4426950408889634f)
#define LN2F 0.69314718055994531f
#define LSS 32                        // diagonals per superstep
#define NSS 35                        // supersteps: (35-3)*32 > 1022

typedef _Float16 h2 __attribute__((ext_vector_type(2)));

__device__ __forceinline__ unsigned pk(float a, float b) {
    h2 v; v.x = (_Float16)a; v.y = (_Float16)b;
    return __builtin_bit_cast(unsigned, v);
}

#if __has_builtin(__builtin_amdgcn_fdot2)
#define FDOT2(a, b, c) __builtin_amdgcn_fdot2(__builtin_bit_cast(h2, (a)), \
                                              __builtin_bit_cast(h2, (b)), (c), false)
#else
__device__ __forceinline__ float fdot2_sw(unsigned a, unsigned b, float c) {
    h2 ha = __builtin_bit_cast(h2, a), hb = __builtin_bit_cast(h2, b);
    return c + (float)ha.x * (float)hb.x + (float)ha.y * (float)hb.y;
}
#define FDOT2(a, b, c) fdot2_sw((a), (b), (c))
#endif

// ---------------------------------------------------------------------------
// Skewed multi-wave fused SoftDTW. One block (256 thr = 4 waves) per sample.
// Wave w owns row band [128w, 128w+128); lane t owns rows 128w+2t, 128w+2t+1.
// Wave w lags wave w-1 by LSS diagonals; band-seam values (bottom row of the
// band above) flow through LDS rings seam[w] (ring 128, init BIGS = matrix
// border); one __syncthreads per superstep (LSS diagonals). Z columns ride a
// 2-slot register queue per lane (one slot shifts up one lane per diagonal;
// lane 0 refills from LDS). D recomputed on the fly (fp16 dot). Base-2
// scaled domain (values = true * log2e). Rationale: rounds 3/5 measured
// ~82% per-SIMD VALU issue-bound at 8 cells/lane -> split the issue load
// across 4 waves (2 cells/lane) and use 4x the SIMDs per sample.
// ---------------------------------------------------------------------------
__global__ __launch_bounds__(256, 1) void k_fused(const float* __restrict__ X,
                                                  const float* __restrict__ Z,
                                                  const float* __restrict__ w,
                                                  float* __restrict__ out) {
    const int tt = threadIdx.x;
    const int t  = tt & 63;          // lane
    const int wv = tt >> 6;          // wave = row band 0..3
    const int n  = blockIdx.x;       // sample

    __shared__ uint4 ZhU[1024];      // Z rows as 8 x h2 (2 uint4 per row)
    __shared__ float Zs2f[512];      // LOG2E * |z_row|^2
    __shared__ float seam[4][128];   // ring w: bottom-row results of band w-1
                                     // (seam[0] never written -> BIGS border)

    // ---- stage Z into LDS: thread tt handles rows tt, tt+256 ----
#pragma unroll
    for (int h = 0; h < 2; ++h) {
        const int r = tt + h * 256;
        const float4* zp = (const float4*)(Z + (size_t)r * 16);
        const float4 a0 = zp[0], a1 = zp[1], a2 = zp[2], a3 = zp[3];
        float sv = 0.0f;
        sv = fmaf(a0.x, a0.x, sv); sv = fmaf(a0.y, a0.y, sv);
        sv = fmaf(a0.z, a0.z, sv); sv = fmaf(a0.w, a0.w, sv);
        sv = fmaf(a1.x, a1.x, sv); sv = fmaf(a1.y, a1.y, sv);
        sv = fmaf(a1.z, a1.z, sv); sv = fmaf(a1.w, a1.w, sv);
        sv = fmaf(a2.x, a2.x, sv); sv = fmaf(a2.y, a2.y, sv);
        sv = fmaf(a2.z, a2.z, sv); sv = fmaf(a2.w, a2.w, sv);
        sv = fmaf(a3.x, a3.x, sv); sv = fmaf(a3.y, a3.y, sv);
        sv = fmaf(a3.z, a3.z, sv); sv = fmaf(a3.w, a3.w, sv);
        ZhU[2 * r]     = make_uint4(pk(a0.x, a0.y), pk(a0.z, a0.w),
                                    pk(a1.x, a1.y), pk(a1.z, a1.w));
        ZhU[2 * r + 1] = make_uint4(pk(a2.x, a2.y), pk(a2.z, a2.w),
                                    pk(a3.x, a3.y), pk(a3.z, a3.w));
        Zs2f[r] = LOG2E * sv;
    }
    // seam rings -> BIGS (matrix top border + "not yet written" safety)
    for (int i = tt; i < 4 * 128; i += 256) (&seam[0][0])[i] = BIGS;

    // ---- X rows for this lane (band rows 2t, 2t+1) -> registers ----
    unsigned Xu[2][8];
    float    xs2[2];
    const float* xp = X + ((size_t)n * TT + 128 * wv + 2 * t) * 16;
#pragma unroll
    for (int q = 0; q < 2; ++q) {
        const float4* xr = (const float4*)(xp + q * 16);
        const float4 a0 = xr[0], a1 = xr[1], a2 = xr[2], a3 = xr[3];
        float sv = 0.0f;
        sv = fmaf(a0.x, a0.x, sv); sv = fmaf(a0.y, a0.y, sv);
        sv = fmaf(a0.z, a0.z, sv); sv = fmaf(a0.w, a0.w, sv);
        sv = fmaf(a1.x, a1.x, sv); sv = fmaf(a1.y, a1.y, sv);
        sv = fmaf(a1.z, a1.z, sv); sv = fmaf(a1.w, a1.w, sv);
        sv = fmaf(a2.x, a2.x, sv); sv = fmaf(a2.y, a2.y, sv);
        sv = fmaf(a2.z, a2.z, sv); sv = fmaf(a2.w, a2.w, sv);
        sv = fmaf(a3.x, a3.x, sv); sv = fmaf(a3.y, a3.y, sv);
        sv = fmaf(a3.z, a3.z, sv); sv = fmaf(a3.w, a3.w, sv);
        xs2[q] = LOG2E * sv;
        Xu[q][0] = pk(a0.x, a0.y); Xu[q][1] = pk(a0.z, a0.w);
        Xu[q][2] = pk(a1.x, a1.y); Xu[q][3] = pk(a1.z, a1.w);
        Xu[q][4] = pk(a2.x, a2.y); Xu[q][5] = pk(a2.z, a2.w);
        Xu[q][6] = pk(a3.x, a3.y); Xu[q][7] = pk(a3.z, a3.w);
    }
    const float wgt = w[n];
    __syncthreads();

    unsigned Zu[2][8];               // 2-slot Z column queue
    float    Zq2[2];
    float A[2] = {BIGS, BIGS}, B[2] = {BIGS, BIGS};
    float finalV = 0.0f;
    const int start = 128 * wv;      // first diagonal touching this band

    // One diagonal d (global), dl = d - start local. pp = dl&1 (structural).
    // Slot map: cell q=0 <-> slot pp, q=1 <-> slot 1-pp; slot 1-pp shifts.
    // P = results diag d-1, Q = diag d-2 (overwritten with diag d).
#define STEP(pp, P, Q, dv)                                                     \
    {                                                                          \
        const int dl = (dv) - start;                                           \
        /* D' for the 2 cells from the register queue */                       \
        float acc0 = 0.0f, acc1 = 0.0f;                                        \
        _Pragma("unroll")                                                      \
        for (int r = 0; r < 8; ++r) {                                          \
            acc0 = FDOT2(Zu[(pp)][r],     Xu[0][r], acc0);                     \
            acc1 = FDOT2(Zu[1 - (pp)][r], Xu[1][r], acc1);                     \
        }                                                                      \
        const float dd0 = fmaf(M2L, acc0, xs2[0] + Zq2[(pp)]);                 \
        const float dd1 = fmaf(M2L, acc1, xs2[1] + Zq2[1 - (pp)]);             \
        /* boundary: lane t-1's rows, lane 0 from the seam ring */             \
        float s1v = __shfl_up(P[1], 1);                                        \
        float s2v = __shfl_up(Q[1], 1);                                        \
        if (t == 0) {                                                          \
            s1v = seam[wv][((dv) - 1) & 127];                                  \
            s2v = seam[wv][((dv) - 2) & 127];                                  \
        }                                                                      \
        /* refill + shift queue slot 1-pp toward diag dl+1 (used next step) */ \
        {                                                                      \
            const int fr = (dl + 1 > 511) ? 511 : (dl + 1);                    \
            const uint4 f0 = ZhU[2 * fr], f1 = ZhU[2 * fr + 1];                \
            const float fz2 = Zs2f[fr];                                        \
            const unsigned fu[8] = {f0.x, f0.y, f0.z, f0.w,                    \
                                    f1.x, f1.y, f1.z, f1.w};                   \
            _Pragma("unroll")                                                  \
            for (int r = 0; r < 8; ++r) {                                      \
                const unsigned sh = __shfl_up(Zu[1 - (pp)][r], 1);             \
                Zu[1 - (pp)][r] = (t == 0) ? fu[r] : sh;                       \
            }                                                                  \
            const float shz = __shfl_up(Zq2[1 - (pp)], 1);                     \
            Zq2[1 - (pp)] = (t == 0) ? fz2 : shz;                              \
        }                                                                      \
        /* softmin, q=1 then q=0 (q=1 reads old Q[0]) */                       \
        {                                                                      \
            const float u1 = P[0], u2 = Q[0], pl = P[1];                       \
            const float mn = fminf(fminf(u1, pl), u2);                         \
            const float md = __builtin_amdgcn_fmed3f(u1, pl, u2);              \
            const float mx = fmaxf(fmaxf(u1, pl), u2);                         \
            const float sm = 1.0f + exp2f(mn - md) + exp2f(mn - mx);           \
            Q[1] = dd1 + mn - log2f(sm);                                       \
        }                                                                      \
        {                                                                      \
            const float u1 = s1v, u2 = s2v, pl = P[0];                         \
            const float mn = fminf(fminf(u1, pl), u2);                         \
            const float md = __builtin_amdgcn_fmed3f(u1, pl, u2);              \
            const float mx = fmaxf(fmaxf(u1, pl), u2);                         \
            const float sm = 1.0f + exp2f(mn - md) + exp2f(mn - mx);           \
            Q[0] = dd0 + mn - log2f(sm);                                       \
        }                                                                      \
        /* j==0 edge repair: row i = dv, cell (2t+q == dl), q == pp */         \
        if (dl < 128 && t == (dl >> 1)) {                                      \
            if ((pp) == 0) Q[0] = dd0 + (((dv) == 0) ? 0.0f : s1v);            \
            else           Q[1] = dd1 + P[0];                                  \
        }                                                                      \
        /* seam write: band bottom row (lane 63, q=1), post-repair */          \
        if (wv < 3 && dl >= 127 && t == 63) seam[wv + 1][(dv) & 127] = Q[1];   \
        /* final cell (511,511) at d=1022 */                                   \
        if (wv == 3 && (dv) == 1022 && t == 63) finalV = Q[1];                 \
    }

#pragma unroll 1
    for (int s = 0; s < NSS; ++s) {
        if (s == 5 * wv) {
            // activation: init queue; lane0/slot0 must be exact z-row 0
            const uint4 q0 = ZhU[0], q1 = ZhU[1];
            const float qz = Zs2f[0];
            const unsigned fu[8] = {q0.x, q0.y, q0.z, q0.w,
                                    q1.x, q1.y, q1.z, q1.w};
#pragma unroll
            for (int sl = 0; sl < 2; ++sl) {
#pragma unroll
                for (int r = 0; r < 8; ++r) Zu[sl][r] = fu[r];
                Zq2[sl] = qz;
            }
        }
        const int dbase = (s - wv) * LSS;
#pragma unroll 2
        for (int mp = 0; mp < LSS / 2; ++mp) {
            const int d0 = dbase + 2 * mp;
            if (d0 >= start && d0 <= start + 638) STEP(0, A, B, d0)
            const int d1 = d0 + 1;
            if (d1 >= start && d1 <= start + 638) STEP(1, B, A, d1)
        }
        __syncthreads();
    }
#undef STEP

    if (wv == 3 && t == 63) atomicAdd(out, wgt * finalV * LN2F);
}

__global__ void k_zero(float* out) {
    if (threadIdx.x == 0) out[0] = 0.0f;
}

extern "C" void kernel_launch(void* const* d_in, const int* in_sizes, int n_in,
                              void* d_out, int out_size, void* d_ws, size_t ws_size,
                              hipStream_t stream) {
    const float* X = (const float*)d_in[0];   // (64, 512, 16) f32
    const float* w = (const float*)d_in[1];   // (64,) f32
    const float* Z = (const float*)d_in[2];   // (512, 16) f32
    float* out = (float*)d_out;               // scalar f32

    hipLaunchKernelGGL(k_zero, dim3(1), dim3(64), 0, stream, out);
    hipLaunchKernelGGL(k_fused, dim3(64), dim3(256), 0, stream, X, Z, w, out);
}

// Round 7
// 376.759 us; speedup vs baseline: 3.3281x; 1.2391x over previous
//
#include <hip/hip_runtime.h>

#define TT 512
#define BIGS 1.4426950408889634e10f   // BIG(1e10) * log2(e), scaled domain
#define LOG2E 1.4426950408889634f
#define M2L  (-2.0f * 1.4426950408889634f)
#define LN2F 0.69314718055994531f
#define LSS 32                        // diagonals per superstep
#define NSS 35                        // ceil: wave 3 finishes diag 1022 at s=34

typedef _Float16 h2 __attribute__((ext_vector_type(2)));

__device__ __forceinline__ unsigned pk(float a, float b) {
    h2 v; v.x = (_Float16)a; v.y = (_Float16)b;
    return __builtin_bit_cast(unsigned, v);
}

#if __has_builtin(__builtin_amdgcn_fdot2)
#define FDOT2(a, b, c) __builtin_amdgcn_fdot2(__builtin_bit_cast(h2, (a)), \
                                              __builtin_bit_cast(h2, (b)), (c), false)
#else
__device__ __forceinline__ float fdot2_sw(unsigned a, unsigned b, float c) {
    h2 ha = __builtin_bit_cast(h2, a), hb = __builtin_bit_cast(h2, b);
    return c + (float)ha.x * (float)hb.x + (float)ha.y * (float)hb.y;
}
#define FDOT2(a, b, c) fdot2_sw((a), (b), (c))
#endif

// permuted Z index: consecutive same-parity rows -> consecutive LDS lines
// (lanes step j by -2 -> idx steps -1 -> b128 reads spread over all 8
//  bank groups; clamped lanes broadcast). jv may be out of range; clamp.
#define ZIDX(jv, xout)                                                         \
    { int jc_ = (jv); jc_ = jc_ < 0 ? 0 : (jc_ > 511 ? 511 : jc_);             \
      (xout) = ((jc_ & 1) << 8) | (jc_ >> 1); }

// ---------------------------------------------------------------------------
// Skewed multi-wave fused SoftDTW, round 7: round-6 structure (one block =
// 4 waves = 4 row bands of one sample, seam rings in LDS, 1 barrier per 32
// diagonals) with the Z register queue replaced by direct reads from a
// bit-permuted LDS layout. Row reuse: cell q1's Z row at diag d == cell
// q0's row at diag d-1, so each step loads ONE new row (2 b128 + 1 b32),
// ping-pong buffered with a full step of latency slack. Lane-0 seam values
// prefetched 2 steps ahead via rotating regs (broadcast LDS reads).
// Base-2 scaled domain (values = true * log2e).
// ---------------------------------------------------------------------------
__global__ __launch_bounds__(256, 1) void k_fused(const float* __restrict__ X,
                                                  const float* __restrict__ Z,
                                                  const float* __restrict__ w,
                                                  float* __restrict__ out) {
    const int tt = threadIdx.x;
    const int t  = tt & 63;          // lane
    const int wv = tt >> 6;          // wave = row band 0..3
    const int n  = blockIdx.x;       // sample

    __shared__ uint4 ZA[2][512];     // [half][permuted idx] 16 KiB
    __shared__ float Zs2p[512];      // LOG2E*|z|^2 at permuted idx
    __shared__ float seam[4][128];   // ring w: bottom-row results of band w-1

    // ---- stage Z into LDS: thread tt handles rows tt, tt+256 ----
#pragma unroll
    for (int h = 0; h < 2; ++h) {
        const int r = tt + h * 256;
        const float4* zp = (const float4*)(Z + (size_t)r * 16);
        const float4 a0 = zp[0], a1 = zp[1], a2 = zp[2], a3 = zp[3];
        float sv = 0.0f;
        sv = fmaf(a0.x, a0.x, sv); sv = fmaf(a0.y, a0.y, sv);
        sv = fmaf(a0.z, a0.z, sv); sv = fmaf(a0.w, a0.w, sv);
        sv = fmaf(a1.x, a1.x, sv); sv = fmaf(a1.y, a1.y, sv);
        sv = fmaf(a1.z, a1.z, sv); sv = fmaf(a1.w, a1.w, sv);
        sv = fmaf(a2.x, a2.x, sv); sv = fmaf(a2.y, a2.y, sv);
        sv = fmaf(a2.z, a2.z, sv); sv = fmaf(a2.w, a2.w, sv);
        sv = fmaf(a3.x, a3.x, sv); sv = fmaf(a3.y, a3.y, sv);
        sv = fmaf(a3.z, a3.z, sv); sv = fmaf(a3.w, a3.w, sv);
        const int idx = ((r & 1) << 8) | (r >> 1);
        ZA[0][idx] = make_uint4(pk(a0.x, a0.y), pk(a0.z, a0.w),
                                pk(a1.x, a1.y), pk(a1.z, a1.w));
        ZA[1][idx] = make_uint4(pk(a2.x, a2.y), pk(a2.z, a2.w),
                                pk(a3.x, a3.y), pk(a3.z, a3.w));
        Zs2p[idx] = LOG2E * sv;
    }
    // seam rings -> BIGS (matrix top border + not-yet-written safety)
    for (int i = tt; i < 4 * 128; i += 256) (&seam[0][0])[i] = BIGS;

    // ---- X rows for this lane (band rows i0, i0+1) -> registers ----
    const int i0 = 128 * wv + 2 * t;
    unsigned Xu[2][8];
    float    xs2[2];
    const float* xp = X + ((size_t)n * TT + i0) * 16;
#pragma unroll
    for (int q = 0; q < 2; ++q) {
        const float4* xr = (const float4*)(xp + q * 16);
        const float4 a0 = xr[0], a1 = xr[1], a2 = xr[2], a3 = xr[3];
        float sv = 0.0f;
        sv = fmaf(a0.x, a0.x, sv); sv = fmaf(a0.y, a0.y, sv);
        sv = fmaf(a0.z, a0.z, sv); sv = fmaf(a0.w, a0.w, sv);
        sv = fmaf(a1.x, a1.x, sv); sv = fmaf(a1.y, a1.y, sv);
        sv = fmaf(a1.z, a1.z, sv); sv = fmaf(a1.w, a1.w, sv);
        sv = fmaf(a2.x, a2.x, sv); sv = fmaf(a2.y, a2.y, sv);
        sv = fmaf(a2.z, a2.z, sv); sv = fmaf(a2.w, a2.w, sv);
        sv = fmaf(a3.x, a3.x, sv); sv = fmaf(a3.y, a3.y, sv);
        sv = fmaf(a3.z, a3.z, sv); sv = fmaf(a3.w, a3.w, sv);
        xs2[q] = LOG2E * sv;
        Xu[q][0] = pk(a0.x, a0.y); Xu[q][1] = pk(a0.z, a0.w);
        Xu[q][2] = pk(a1.x, a1.y); Xu[q][3] = pk(a1.z, a1.w);
        Xu[q][4] = pk(a2.x, a2.y); Xu[q][5] = pk(a2.z, a2.w);
        Xu[q][6] = pk(a3.x, a3.y); Xu[q][7] = pk(a3.z, a3.w);
    }
    const float wgt = w[n];
    __syncthreads();

    float A[2] = {BIGS, BIGS}, B[2] = {BIGS, BIGS};
    uint4 Zb[2][2];        // ping-pong: buffered Z row (2 halves)
    float Ss[2];           // its LOG2E*|z|^2
    float smq[2];          // rotating seam values (lane-0 boundary)
    float finalV = 0.0f;
    const int start = 128 * wv;
    const int dmax  = start + 638;

    // STEP for diag dv (pp = dv&1 compile-time). P = diag dv-1, Q = diag
    // dv-2 (overwritten with dv). q0 Z row in Zb[pp] (loaded last step),
    // q1 row in Zb[1-pp] (two steps ago). Afterwards prefetch row dv+1-i0
    // into Zb[1-pp].
#define STEP(pp, P, Q, dv)                                                     \
    {                                                                          \
        float s1v = __shfl_up(P[1], 1);                                        \
        float s2v = __shfl_up(Q[1], 1);                                        \
        if (t == 0) { s1v = smq[1 - (pp)]; s2v = smq[(pp)]; }                  \
        smq[(pp)] = seam[wv][(dv) & 127];   /* for step dv+2 (broadcast) */    \
        /* dd for diag dv from buffered rows */                                \
        const uint4 za0 = Zb[(pp)][0],     za1 = Zb[(pp)][1];                  \
        const uint4 zb0 = Zb[1 - (pp)][0], zb1 = Zb[1 - (pp)][1];              \
        float acc0 = 0.0f, acc1 = 0.0f;                                        \
        acc0 = FDOT2(za0.x, Xu[0][0], acc0);                                   \
        acc0 = FDOT2(za0.y, Xu[0][1], acc0);                                   \
        acc0 = FDOT2(za0.z, Xu[0][2], acc0);                                   \
        acc0 = FDOT2(za0.w, Xu[0][3], acc0);                                   \
        acc0 = FDOT2(za1.x, Xu[0][4], acc0);                                   \
        acc0 = FDOT2(za1.y, Xu[0][5], acc0);                                   \
        acc0 = FDOT2(za1.z, Xu[0][6], acc0);                                   \
        acc0 = FDOT2(za1.w, Xu[0][7], acc0);                                   \
        acc1 = FDOT2(zb0.x, Xu[1][0], acc1);                                   \
        acc1 = FDOT2(zb0.y, Xu[1][1], acc1);                                   \
        acc1 = FDOT2(zb0.z, Xu[1][2], acc1);                                   \
        acc1 = FDOT2(zb0.w, Xu[1][3], acc1);                                   \
        acc1 = FDOT2(zb1.x, Xu[1][4], acc1);                                   \
        acc1 = FDOT2(zb1.y, Xu[1][5], acc1);                                   \
        acc1 = FDOT2(zb1.z, Xu[1][6], acc1);                                   \
        acc1 = FDOT2(zb1.w, Xu[1][7], acc1);                                   \
        const float dd0 = fmaf(M2L, acc0, xs2[0] + Ss[(pp)]);                  \
        const float dd1 = fmaf(M2L, acc1, xs2[1] + Ss[1 - (pp)]);              \
        /* prefetch next q0 row (j = dv+1-i0) into buf[1-pp] */                \
        {                                                                      \
            int xn; ZIDX((dv) + 1 - i0, xn);                                   \
            Zb[1 - (pp)][0] = ZA[0][xn];                                       \
            Zb[1 - (pp)][1] = ZA[1][xn];                                       \
            Ss[1 - (pp)] = Zs2p[xn];                                           \
        }                                                                      \
        /* softmin q=1 (in-lane, reads old Q[0]) then q=0 (cross-lane) */      \
        {                                                                      \
            const float u1 = P[0], u2 = Q[0], pl = P[1];                       \
            const float mn = fminf(fminf(u1, pl), u2);                         \
            const float md = __builtin_amdgcn_fmed3f(u1, pl, u2);              \
            const float mx = fmaxf(fmaxf(u1, pl), u2);                         \
            const float sm = 1.0f + exp2f(mn - md) + exp2f(mn - mx);           \
            Q[1] = dd1 + mn - log2f(sm);                                       \
        }                                                                      \
        {                                                                      \
            const float u1 = s1v, u2 = s2v, pl = P[0];                         \
            const float mn = fminf(fminf(u1, pl), u2);                         \
            const float md = __builtin_amdgcn_fmed3f(u1, pl, u2);              \
            const float mx = fmaxf(fmaxf(u1, pl), u2);                         \
            const float sm = 1.0f + exp2f(mn - md) + exp2f(mn - mx);           \
            Q[0] = dd0 + mn - log2f(sm);                                       \
        }                                                                      \
        const int dl = (dv) - start;                                           \
        /* j==0 edge repair (left/diag are garbage there, up is exact) */      \
        if (dl < 128 && t == (dl >> 1)) {                                      \
            if ((pp) == 0) Q[0] = dd0 + (((dv) == 0) ? 0.0f : s1v);            \
            else           Q[1] = dd1 + P[0];                                  \
        }                                                                      \
        if (wv < 3 && dl >= 127 && t == 63) seam[wv + 1][(dv) & 127] = Q[1];   \
        if (wv == 3 && (dv) == 1022 && t == 63) finalV = Q[1];                 \
    }

#pragma unroll 1
    for (int s = 0; s < NSS; ++s) {
        if (s == 5 * wv) {
            // activation: prime Z row buffers and seam regs for dv = start
            int x0; ZIDX(start - i0, x0);        // q0 row at dv=start
            int x1; ZIDX(start - i0 - 1, x1);    // q1 row at dv=start
            Zb[0][0] = ZA[0][x0]; Zb[0][1] = ZA[1][x0]; Ss[0] = Zs2p[x0];
            Zb[1][0] = ZA[0][x1]; Zb[1][1] = ZA[1][x1]; Ss[1] = Zs2p[x1];
            smq[1] = seam[wv][(start - 1) & 127];   // s1v for dv=start
            smq[0] = seam[wv][(start - 2) & 127];   // s2v for dv=start
        }
        const int dbase = (s - wv) * LSS;
#pragma unroll 2
        for (int mp = 0; mp < LSS / 2; ++mp) {
            const int d0 = dbase + 2 * mp;
            if (d0 >= start && d0 <= dmax) STEP(0, A, B, d0)
            const int d1 = d0 + 1;
            if (d1 >= start && d1 <= dmax) STEP(1, B, A, d1)
        }
        __syncthreads();
    }
#undef STEP

    if (wv == 3 && t == 63) atomicAdd(out, wgt * finalV * LN2F);
}

__global__ void k_zero(float* out) {
    if (threadIdx.x == 0) out[0] = 0.0f;
}

extern "C" void kernel_launch(void* const* d_in, const int* in_sizes, int n_in,
                              void* d_out, int out_size, void* d_ws, size_t ws_size,
                              hipStream_t stream) {
    const float* X = (const float*)d_in[0];   // (64, 512, 16) f32
    const float* w = (const float*)d_in[1];   // (64,) f32
    const float* Z = (const float*)d_in[2];   // (512, 16) f32
    float* out = (float*)d_out;               // scalar f32

    hipLaunchKernelGGL(k_zero, dim3(1), dim3(64), 0, stream, out);
    hipLaunchKernelGGL(k_fused, dim3(64), dim3(256), 0, stream, X, Z, w, out);
}